// Round 2
// baseline (722.569 us; speedup 1.0000x reference)
//
#include <hip/hip_runtime.h>
#include <hip/hip_bf16.h>

#define B_   64
#define CIN  2048
#define COUT 32
#define P    196      // 14*14
#define PPAD 224      // padded pixel count
#define REP  1024
#define K1   (CIN*COUT)  // 65536

typedef float  f32x4  __attribute__((ext_vector_type(4)));
typedef __bf16 bf16x8 __attribute__((ext_vector_type(8)));
typedef __bf16 bf16x4 __attribute__((ext_vector_type(4)));

// ---- workspace layout (bytes), aliased regions ----
// region 1: S [64][9][32][224] f32 (16.5MB)  -> later S1 [64][64][1024] f32 (16.8MB)
#define OFF_R1     0
// region 2: pooled [64][65536] bf16 (8.39MB) -> later S2 [32][64][1024] f32 (8.39MB)
#define OFF_R2     16777216
#define OFF_W2     25165824      // bf16 [9][32][2048]   (1.18MB)
#define OFF_AM     26345472      // f32  [64][32][224]   (1.84MB)
#define OFF_H6B    28180480      // bf16 [64][1024]      (131KB)

static __device__ __forceinline__ f32x4 mfma16(bf16x8 a, bf16x8 b, f32x4 c) {
  return __builtin_amdgcn_mfma_f32_16x16x32_bf16(a, b, c, 0, 0, 0);
}

// ============================================================
// prep_w2: cw[o][cin][d] f32 -> W2[d][o][cin] bf16
// ============================================================
__global__ __launch_bounds__(256)
void prep_w2(const float* __restrict__ cw, __bf16* __restrict__ W2) {
  const int blk = blockIdx.x;            // o*8 + cc
  const int o = blk >> 3, cc = blk & 7;
  const int cin = cc * 256 + threadIdx.x;
  const float* src = cw + ((size_t)o * CIN + cin) * 9;
  #pragma unroll
  for (int d = 0; d < 9; d++)
    W2[((size_t)d * COUT + o) * CIN + cin] = (__bf16)src[d];
}

// ============================================================
// sgemm: S[b][d][o][p] = sum_i W2[d][o][i] * x[b][i][p]
// M=288 (wave=d -> 2 m-tiles), N=32 pixels/block (2 n-tiles), K=2048.
// Barrier-free, no LDS; A from L2-resident W2, B via coalesced scalar x loads.
// grid (7, 64), block 576 (9 waves).
// ============================================================
__global__ __launch_bounds__(576)
void sgemm_kernel(const float* __restrict__ x, const __bf16* __restrict__ W2,
                  float* __restrict__ S) {
  const int nb = blockIdx.x;             // pixel block: nb*32
  const int b  = blockIdx.y;
  const int d  = threadIdx.x >> 6;       // wave = tap
  const int lane = threadIdx.x & 63;
  const int q = lane >> 4, ln = lane & 15;
  const int n0 = nb * 32;
  const int p0 = n0 + ln, p1 = n0 + 16 + ln;

  const __bf16* A  = W2 + (size_t)d * COUT * CIN;
  const float*  xb = x + (size_t)b * CIN * P;

  f32x4 acc[2][2];
  #pragma unroll
  for (int m = 0; m < 2; m++)
    #pragma unroll
    for (int n = 0; n < 2; n++) { f32x4 z = {0.f,0.f,0.f,0.f}; acc[m][n] = z; }

  if (nb < 6) {
    #pragma unroll 2
    for (int kc = 0; kc < 64; kc++) {
      const int k0 = kc * 32 + q * 8;
      bf16x8 a0 = *(const bf16x8*)&A[(size_t)ln * CIN + k0];
      bf16x8 a1 = *(const bf16x8*)&A[(size_t)(16 + ln) * CIN + k0];
      bf16x8 b0, b1;
      const float* xk = xb + (size_t)k0 * P;
      #pragma unroll
      for (int j = 0; j < 8; j++) {
        b0[j] = (__bf16)xk[(size_t)j * P + p0];
        b1[j] = (__bf16)xk[(size_t)j * P + p1];
      }
      acc[0][0] = mfma16(a0, b0, acc[0][0]);
      acc[0][1] = mfma16(a0, b1, acc[0][1]);
      acc[1][0] = mfma16(a1, b0, acc[1][0]);
      acc[1][1] = mfma16(a1, b1, acc[1][1]);
    }
  } else {
    // tail pixel block (192..223): mask x loads past P
    #pragma unroll 2
    for (int kc = 0; kc < 64; kc++) {
      const int k0 = kc * 32 + q * 8;
      bf16x8 a0 = *(const bf16x8*)&A[(size_t)ln * CIN + k0];
      bf16x8 a1 = *(const bf16x8*)&A[(size_t)(16 + ln) * CIN + k0];
      bf16x8 b0, b1;
      const float* xk = xb + (size_t)k0 * P;
      #pragma unroll
      for (int j = 0; j < 8; j++) {
        b0[j] = (p0 < P) ? (__bf16)xk[(size_t)j * P + p0] : (__bf16)0.f;
        b1[j] = (__bf16)0.f;   // p1 >= 208 always invalid
      }
      acc[0][0] = mfma16(a0, b0, acc[0][0]);
      acc[0][1] = mfma16(a0, b1, acc[0][1]);
      acc[1][0] = mfma16(a1, b0, acc[1][0]);
      acc[1][1] = mfma16(a1, b1, acc[1][1]);
    }
  }

  #pragma unroll
  for (int mt = 0; mt < 2; mt++)
    #pragma unroll
    for (int nt = 0; nt < 2; nt++) {
      const int p = n0 + nt * 16 + ln;
      float* dst = &S[(((size_t)b * 9 + d) * COUT + mt * 16 + q * 4) * PPAD + p];
      #pragma unroll
      for (int r = 0; r < 4; r++) dst[(size_t)r * PPAD] = acc[mt][nt][r];
    }
}

// ============================================================
// combine: am[b][o][p] = sum_{dy,dx} S[b][dy*3+dx][o][shifted p] (masked),
// pad pixels (p>=196) written as 0. grid 256 (= 64 b x 4 parts), block 256.
// ============================================================
__global__ __launch_bounds__(256)
void combine_kernel(const float* __restrict__ S, float* __restrict__ am) {
  const int b = blockIdx.x >> 2, part = blockIdx.x & 3;
  const float* Sb = S + (size_t)b * 9 * COUT * PPAD;
  for (int i = threadIdx.x; i < 1792; i += 256) {
    const int idx = part * 1792 + i;        // 0..7167 over [o][p]
    const int o = idx / PPAD, p = idx - o * PPAD;
    float s = 0.f;
    if (p < P) {
      const int h = p / 14, w = p - (p / 14) * 14;
      #pragma unroll
      for (int dy = 0; dy < 3; dy++)
        #pragma unroll
        for (int dx = 0; dx < 3; dx++) {
          const int hh = h + dy - 1, ww = w + dx - 1;
          if (hh >= 0 && hh < 14 && ww >= 0 && ww < 14)
            s += Sb[((size_t)(dy * 3 + dx) * COUT + o) * PPAD + hh * 14 + ww];
        }
    }
    am[((size_t)b * COUT + o) * PPAD + p] = s;
  }
}

// ============================================================
// pooled[b][i*32+o] = bf16( (1/196) sum_p (am[b,o,p]+cb[o]) * x[b,i,p] )
// grid (16, 64), block 256; wave: 32 i (2 n-tiles) x 32 o (2 m-tiles).
// ============================================================
__global__ __launch_bounds__(256)
void pooled_kernel(const float* __restrict__ x, const float* __restrict__ amp,
                   const float* __restrict__ cb, __bf16* __restrict__ pooled) {
  const int b  = blockIdx.y;
  const int ig = blockIdx.x;
  const int t  = threadIdx.x;
  const int wv = t >> 6;
  const int lane = t & 63;
  const int q = lane >> 4, ln = lane & 15;
  const int ibase = ig * 128 + wv * 32;

  f32x4 acc[2][2];
  #pragma unroll
  for (int a = 0; a < 2; a++)
    #pragma unroll
    for (int c = 0; c < 2; c++) { f32x4 z = {0.f,0.f,0.f,0.f}; acc[a][c] = z; }

  const float* amb = amp + (size_t)b * COUT * PPAD;
  const float* xb  = x + (size_t)b * CIN * P;
  const float cbv[2] = { cb[ln], cb[16 + ln] };

  for (int kc = 0; kc < 7; kc++) {
    const int k0 = kc * 32 + q * 8;
    bf16x8 af[2];
    #pragma unroll
    for (int o2 = 0; o2 < 2; o2++) {
      const float* src = &amb[(size_t)(o2 * 16 + ln) * PPAD + k0];
      f32x4 v0 = *(const f32x4*)src;
      f32x4 v1 = *(const f32x4*)(src + 4);
      bf16x8 a;
      #pragma unroll
      for (int j = 0; j < 4; j++) { a[j] = (__bf16)(v0[j] + cbv[o2]); a[4 + j] = (__bf16)(v1[j] + cbv[o2]); }
      af[o2] = a;
    }
    #pragma unroll
    for (int it = 0; it < 2; it++) {
      const int i = ibase + it * 16 + ln;
      bf16x8 bfr;
      if (kc < 6) {
        const float* src = &xb[(size_t)i * P + k0];
        f32x4 v0 = *(const f32x4*)src;
        f32x4 v1 = *(const f32x4*)(src + 4);
        #pragma unroll
        for (int j = 0; j < 4; j++) { bfr[j] = (__bf16)v0[j]; bfr[4 + j] = (__bf16)v1[j]; }
      } else {
        #pragma unroll
        for (int j = 0; j < 8; j++) {
          const int p = k0 + j;
          bfr[j] = (p < P) ? (__bf16)xb[(size_t)i * P + p] : (__bf16)0.f;
        }
      }
      acc[0][it] = mfma16(af[0], bfr, acc[0][it]);
      acc[1][it] = mfma16(af[1], bfr, acc[1][it]);
    }
  }

  const float sc = 1.0f / 196.0f;
  #pragma unroll
  for (int o2 = 0; o2 < 2; o2++)
    #pragma unroll
    for (int it = 0; it < 2; it++) {
      const int i = ibase + it * 16 + ln;
      bf16x4 vv;
      #pragma unroll
      for (int r = 0; r < 4; r++) vv[r] = (__bf16)(acc[o2][it][r] * sc);
      *(bf16x4*)&pooled[(size_t)b * K1 + (size_t)i * COUT + o2 * 16 + q * 4] = vv;
    }
}

// ============================================================
// gemm1: S1[ks][m][n] = pooled[m][ks-range] @ w6[n][ks-range]^T
// grid (16 nb, 64 ks), block 256; wave = 16-col n-tile, 4 m-tiles. No atomics.
// ============================================================
__global__ __launch_bounds__(256)
void gemm1_kernel(const __bf16* __restrict__ pooled, const float* __restrict__ w6,
                  float* __restrict__ S1) {
  const int nb = blockIdx.x, ks = blockIdx.y;
  const int t = threadIdx.x;
  const int wv = t >> 6;
  const int lane = t & 63;
  const int q = lane >> 4, ln = lane & 15;
  const int n0 = nb * 64 + wv * 16;
  const int kbase = ks * 1024;

  f32x4 acc[4];
  #pragma unroll
  for (int a = 0; a < 4; a++) { f32x4 z = {0.f,0.f,0.f,0.f}; acc[a] = z; }

  #pragma unroll 2
  for (int kc = 0; kc < 32; kc++) {
    const int k0 = kbase + kc * 32 + q * 8;
    const float* src = &w6[(size_t)(n0 + ln) * K1 + k0];
    f32x4 v0 = *(const f32x4*)src;
    f32x4 v1 = *(const f32x4*)(src + 4);
    bf16x8 bfr;
    #pragma unroll
    for (int j = 0; j < 4; j++) { bfr[j] = (__bf16)v0[j]; bfr[4 + j] = (__bf16)v1[j]; }
    #pragma unroll
    for (int mi = 0; mi < 4; mi++) {
      bf16x8 af = *(const bf16x8*)&pooled[(size_t)(mi * 16 + ln) * K1 + k0];
      acc[mi] = mfma16(af, bfr, acc[mi]);
    }
  }
  #pragma unroll
  for (int mi = 0; mi < 4; mi++)
    #pragma unroll
    for (int r = 0; r < 4; r++)
      S1[(size_t)ks * (B_ * REP) + (size_t)(mi * 16 + q * 4 + r) * REP + n0 + ln] = acc[mi][r];
}

// ============================================================
// reduce1: h6b[m][n] = bf16(relu(sum_ks S1[ks][m][n] + b6[n]))
// ============================================================
__global__ __launch_bounds__(256)
void reduce1_kernel(const float* __restrict__ S1, const float* __restrict__ b6,
                    __bf16* __restrict__ h6b) {
  const int idx = blockIdx.x * 256 + threadIdx.x;     // 65536
  float s = 0.f;
  #pragma unroll 8
  for (int ks = 0; ks < 64; ks++) s += S1[(size_t)ks * (B_ * REP) + idx];
  h6b[idx] = (__bf16)fmaxf(s + b6[idx & (REP - 1)], 0.f);
}

// ============================================================
// gemm2: S2[ks][m][n] partials of h6b @ w7^T. grid (16 nb, 32 ks), block 256.
// ============================================================
__global__ __launch_bounds__(256)
void gemm2_kernel(const __bf16* __restrict__ h6b, const float* __restrict__ w7,
                  float* __restrict__ S2) {
  const int nb = blockIdx.x, ks = blockIdx.y;
  const int t = threadIdx.x;
  const int wv = t >> 6;
  const int lane = t & 63;
  const int q = lane >> 4, ln = lane & 15;
  const int n0 = nb * 64 + wv * 16;
  const int k0 = ks * 32 + q * 8;

  const float* src = &w7[(size_t)(n0 + ln) * REP + k0];
  f32x4 v0 = *(const f32x4*)src;
  f32x4 v1 = *(const f32x4*)(src + 4);
  bf16x8 bfr;
  #pragma unroll
  for (int j = 0; j < 4; j++) { bfr[j] = (__bf16)v0[j]; bfr[4 + j] = (__bf16)v1[j]; }

  f32x4 acc[4];
  #pragma unroll
  for (int mi = 0; mi < 4; mi++) {
    f32x4 z = {0.f,0.f,0.f,0.f};
    bf16x8 af = *(const bf16x8*)&h6b[(size_t)(mi * 16 + ln) * REP + k0];
    acc[mi] = mfma16(af, bfr, z);
  }
  #pragma unroll
  for (int mi = 0; mi < 4; mi++)
    #pragma unroll
    for (int r = 0; r < 4; r++)
      S2[(size_t)ks * (B_ * REP) + (size_t)(mi * 16 + q * 4 + r) * REP + n0 + ln] = acc[mi][r];
}

// ============================================================
// reduce2: out[m][n] = relu(sum_ks S2 + b7[n])
// ============================================================
__global__ __launch_bounds__(256)
void reduce2_kernel(const float* __restrict__ S2, const float* __restrict__ b7,
                    float* __restrict__ out) {
  const int idx = blockIdx.x * 256 + threadIdx.x;
  float s = 0.f;
  #pragma unroll 8
  for (int ks = 0; ks < 32; ks++) s += S2[(size_t)ks * (B_ * REP) + idx];
  out[idx] = fmaxf(s + b7[idx & (REP - 1)], 0.f);
}

extern "C" void kernel_launch(void* const* d_in, const int* in_sizes, int n_in,
                              void* d_out, int out_size, void* d_ws, size_t ws_size,
                              hipStream_t stream) {
  const float* x   = (const float*)d_in[0];
  const float* cw  = (const float*)d_in[1];
  const float* cb  = (const float*)d_in[2];
  const float* w6  = (const float*)d_in[3];
  const float* b6  = (const float*)d_in[4];
  const float* w7  = (const float*)d_in[5];
  const float* b7  = (const float*)d_in[6];
  float* out = (float*)d_out;

  char* ws = (char*)d_ws;
  float*  S      = (float*)(ws + OFF_R1);   // then S1
  float*  S1     = (float*)(ws + OFF_R1);
  __bf16* pooled = (__bf16*)(ws + OFF_R2);  // then S2
  float*  S2     = (float*)(ws + OFF_R2);
  __bf16* W2     = (__bf16*)(ws + OFF_W2);
  float*  am     = (float*)(ws + OFF_AM);
  __bf16* h6b    = (__bf16*)(ws + OFF_H6B);

  prep_w2       <<<256,          256, 0, stream>>>(cw, W2);
  sgemm_kernel  <<<dim3(7, 64),  576, 0, stream>>>(x, W2, S);
  combine_kernel<<<256,          256, 0, stream>>>(S, am);
  pooled_kernel <<<dim3(16, 64), 256, 0, stream>>>(x, am, cb, pooled);
  gemm1_kernel  <<<dim3(16, 64), 256, 0, stream>>>(pooled, w6, S1);
  reduce1_kernel<<<256,          256, 0, stream>>>(S1, b6, h6b);
  gemm2_kernel  <<<dim3(16, 32), 256, 0, stream>>>(h6b, w7, S2);
  reduce2_kernel<<<256,          256, 0, stream>>>(S2, b7, out);
}

// Round 3
// 655.166 us; speedup vs baseline: 1.1029x; 1.1029x over previous
//
#include <hip/hip_runtime.h>
#include <hip/hip_bf16.h>

#define B_   64
#define CIN  2048
#define COUT 32
#define P    196      // 14*14
#define PPAD 224      // padded pixel count
#define REP  1024
#define K1   (CIN*COUT)  // 65536

typedef float  f32x4  __attribute__((ext_vector_type(4)));
typedef __bf16 bf16x8 __attribute__((ext_vector_type(8)));
typedef __bf16 bf16x4 __attribute__((ext_vector_type(4)));

// ---- workspace layout (bytes), aliased regions ----
#define OFF_XT     0                       // bf16 [64][224][2048] (58.7MB); later S1 f32 [64][64][1024] (16.8MB)
#define OFF_S      58720256                // f32  [64][288][224]  (16.5MB)
#define OFF_R2     75235328                // bf16 pooled [64][65536] (8.4MB); later S2 f32 [32][64][1024]
#define OFF_W2     83623936                // bf16 [9][32][2048]   (1.18MB)
#define OFF_AM     84803584                // f32  [64][32][224]   (1.84MB)
#define OFF_H6B    86638592                // bf16 [64][1024]      (131KB)

static __device__ __forceinline__ f32x4 mfma16(bf16x8 a, bf16x8 b, f32x4 c) {
  return __builtin_amdgcn_mfma_f32_16x16x32_bf16(a, b, c, 0, 0, 0);
}

// ============================================================
// prep_w2: cw[o][cin][d] f32 -> W2[d*32+o][cin] bf16  (rows = GEMM M dim)
// ============================================================
__global__ __launch_bounds__(256)
void prep_w2(const float* __restrict__ cw, __bf16* __restrict__ W2) {
  const int blk = blockIdx.x;            // o*8 + cc
  const int o = blk >> 3, cc = blk & 7;
  const int cin = cc * 256 + threadIdx.x;
  const float* src = cw + ((size_t)o * CIN + cin) * 9;
  #pragma unroll
  for (int d = 0; d < 9; d++)
    W2[((size_t)d * COUT + o) * CIN + cin] = (__bf16)src[d];
}

// ============================================================
// txp: x[b][i][p] f32 -> xT[b][p(224, zero-pad)][i] bf16
// LDS-tiled transpose, 128i x 64p per block. grid (64, 64), block 256.
// ============================================================
__global__ __launch_bounds__(256)
void txp_kernel(const float* __restrict__ x, __bf16* __restrict__ xT) {
  __shared__ __bf16 T[64][130];          // [p_local][i_local], stride 130 (pad)
  const int b  = blockIdx.y;
  const int ic = blockIdx.x >> 2;        // 16 i-chunks of 128
  const int pc = blockIdx.x & 3;         // 4 p-chunks of 64
  const int i0 = ic * 128, p0 = pc * 64;
  const int t  = threadIdx.x;
  const int c4 = t & 15, rr = t >> 4;
  const int pl4 = c4 * 4;
  const int p   = p0 + pl4;
  const float* xrow0 = x + ((size_t)b * CIN + i0) * P;

  #pragma unroll
  for (int pass = 0; pass < 8; pass++) {
    const int ii = rr + pass * 16;       // i_local
    __bf16 bv[4];
    if (p < P) {                         // p multiple of 4; p<=192 => p+3<=195<P, full f32x4 ok
      f32x4 v = *(const f32x4*)&xrow0[(size_t)ii * P + p];
      #pragma unroll
      for (int j = 0; j < 4; j++) bv[j] = (__bf16)v[j];
    } else {
      #pragma unroll
      for (int j = 0; j < 4; j++) bv[j] = (__bf16)0.f;
    }
    #pragma unroll
    for (int j = 0; j < 4; j++) T[pl4 + j][ii] = bv[j];
  }
  __syncthreads();
  const int ln8 = t & 15, pr = t >> 4;
  #pragma unroll
  for (int pass = 0; pass < 4; pass++) {
    const int pl = pr + pass * 16;
    const int pg = p0 + pl;
    if (pg < PPAD) {
      bf16x8 v = *(const bf16x8*)&T[pl][ln8 * 8];
      *(bf16x8*)&xT[((size_t)b * PPAD + pg) * CIN + i0 + ln8 * 8] = v;
    }
  }
}

// ============================================================
// sgemm: S[b][m=d*32+o][p] = sum_i W2[m][i] * xT[b][p][i]
// M=288 (18 m-tiles), N=224 (block=32 p), K=2048. All loads bf16x8 (16B/lane).
// grid (7, 64), block 384 (6 waves x 3 m-tiles x 2 n-tiles). No LDS/barriers.
// ============================================================
__global__ __launch_bounds__(384)
void sgemm_kernel(const __bf16* __restrict__ xT, const __bf16* __restrict__ W2,
                  float* __restrict__ S) {
  const int nb = blockIdx.x;             // p0 = nb*32
  const int b  = blockIdx.y;
  const int wv = threadIdx.x >> 6;       // 0..5
  const int lane = threadIdx.x & 63;
  const int q = lane >> 4, ln = lane & 15;
  const int n0 = nb * 32;
  const int mt0 = wv * 3;
  const __bf16* xTb = xT + (size_t)b * PPAD * CIN;

  f32x4 acc[3][2];
  #pragma unroll
  for (int m = 0; m < 3; m++)
    #pragma unroll
    for (int n = 0; n < 2; n++) { f32x4 z = {0.f,0.f,0.f,0.f}; acc[m][n] = z; }

  #pragma unroll 2
  for (int kc = 0; kc < 64; kc++) {
    const int k0 = kc * 32 + q * 8;
    bf16x8 bf0 = *(const bf16x8*)&xTb[(size_t)(n0 + ln) * CIN + k0];
    bf16x8 bf1 = *(const bf16x8*)&xTb[(size_t)(n0 + 16 + ln) * CIN + k0];
    #pragma unroll
    for (int m = 0; m < 3; m++) {
      bf16x8 af = *(const bf16x8*)&W2[(size_t)((mt0 + m) * 16 + ln) * CIN + k0];
      acc[m][0] = mfma16(af, bf0, acc[m][0]);
      acc[m][1] = mfma16(af, bf1, acc[m][1]);
    }
  }

  #pragma unroll
  for (int m = 0; m < 3; m++)
    #pragma unroll
    for (int nt = 0; nt < 2; nt++)
      #pragma unroll
      for (int r = 0; r < 4; r++)
        S[((size_t)b * 288 + (mt0 + m) * 16 + q * 4 + r) * PPAD + n0 + nt * 16 + ln]
          = acc[m][nt][r];
}

// ============================================================
// combine: am[b][o][p] = sum_{dy,dx} S[b][(dy*3+dx)*32+o][shifted p] (masked),
// pad pixels (p>=196) written as 0. grid 256, block 256.
// ============================================================
__global__ __launch_bounds__(256)
void combine_kernel(const float* __restrict__ S, float* __restrict__ am) {
  const int b = blockIdx.x >> 2, part = blockIdx.x & 3;
  const float* Sb = S + (size_t)b * 288 * PPAD;
  for (int i = threadIdx.x; i < 1792; i += 256) {
    const int idx = part * 1792 + i;        // over [o][p]
    const int o = idx / PPAD, p = idx - o * PPAD;
    float s = 0.f;
    if (p < P) {
      const int h = p / 14, w = p - (p / 14) * 14;
      #pragma unroll
      for (int dy = 0; dy < 3; dy++)
        #pragma unroll
        for (int dx = 0; dx < 3; dx++) {
          const int hh = h + dy - 1, ww = w + dx - 1;
          if (hh >= 0 && hh < 14 && ww >= 0 && ww < 14)
            s += Sb[((size_t)(dy * 3 + dx) * COUT + o) * PPAD + hh * 14 + ww];
        }
    }
    am[((size_t)b * COUT + o) * PPAD + p] = s;
  }
}

// ============================================================
// pooled[b][i*32+o] = bf16( (1/196) sum_p (am[b,o,p]+cb[o]) * x[b,i,p] )
// grid (16, 64), block 256; wave: 32 i x 32 o.
// ============================================================
__global__ __launch_bounds__(256)
void pooled_kernel(const float* __restrict__ x, const float* __restrict__ amp,
                   const float* __restrict__ cb, __bf16* __restrict__ pooled) {
  const int b  = blockIdx.y;
  const int ig = blockIdx.x;
  const int t  = threadIdx.x;
  const int wv = t >> 6;
  const int lane = t & 63;
  const int q = lane >> 4, ln = lane & 15;
  const int ibase = ig * 128 + wv * 32;

  f32x4 acc[2][2];
  #pragma unroll
  for (int a = 0; a < 2; a++)
    #pragma unroll
    for (int c = 0; c < 2; c++) { f32x4 z = {0.f,0.f,0.f,0.f}; acc[a][c] = z; }

  const float* amb = amp + (size_t)b * COUT * PPAD;
  const float* xb  = x + (size_t)b * CIN * P;
  const float cbv[2] = { cb[ln], cb[16 + ln] };

  for (int kc = 0; kc < 7; kc++) {
    const int k0 = kc * 32 + q * 8;
    bf16x8 af[2];
    #pragma unroll
    for (int o2 = 0; o2 < 2; o2++) {
      const float* src = &amb[(size_t)(o2 * 16 + ln) * PPAD + k0];
      f32x4 v0 = *(const f32x4*)src;
      f32x4 v1 = *(const f32x4*)(src + 4);
      bf16x8 a;
      #pragma unroll
      for (int j = 0; j < 4; j++) { a[j] = (__bf16)(v0[j] + cbv[o2]); a[4 + j] = (__bf16)(v1[j] + cbv[o2]); }
      af[o2] = a;
    }
    #pragma unroll
    for (int it = 0; it < 2; it++) {
      const int i = ibase + it * 16 + ln;
      bf16x8 bfr;
      if (kc < 6) {
        const float* src = &xb[(size_t)i * P + k0];
        f32x4 v0 = *(const f32x4*)src;
        f32x4 v1 = *(const f32x4*)(src + 4);
        #pragma unroll
        for (int j = 0; j < 4; j++) { bfr[j] = (__bf16)v0[j]; bfr[4 + j] = (__bf16)v1[j]; }
      } else {
        #pragma unroll
        for (int j = 0; j < 8; j++) {
          const int p = k0 + j;
          bfr[j] = (p < P) ? (__bf16)xb[(size_t)i * P + p] : (__bf16)0.f;
        }
      }
      acc[0][it] = mfma16(af[0], bfr, acc[0][it]);
      acc[1][it] = mfma16(af[1], bfr, acc[1][it]);
    }
  }

  const float sc = 1.0f / 196.0f;
  #pragma unroll
  for (int o2 = 0; o2 < 2; o2++)
    #pragma unroll
    for (int it = 0; it < 2; it++) {
      const int i = ibase + it * 16 + ln;
      bf16x4 vv;
      #pragma unroll
      for (int r = 0; r < 4; r++) vv[r] = (__bf16)(acc[o2][it][r] * sc);
      *(bf16x4*)&pooled[(size_t)b * K1 + (size_t)i * COUT + o2 * 16 + q * 4] = vv;
    }
}

// ============================================================
// gemm1: S1[ks][m][n] = pooled[m][ks-range] @ w6[n][ks-range]^T
// grid (16 nb, 64 ks), block 256. No atomics.
// ============================================================
__global__ __launch_bounds__(256)
void gemm1_kernel(const __bf16* __restrict__ pooled, const float* __restrict__ w6,
                  float* __restrict__ S1) {
  const int nb = blockIdx.x, ks = blockIdx.y;
  const int t = threadIdx.x;
  const int wv = t >> 6;
  const int lane = t & 63;
  const int q = lane >> 4, ln = lane & 15;
  const int n0 = nb * 64 + wv * 16;
  const int kbase = ks * 1024;

  f32x4 acc[4];
  #pragma unroll
  for (int a = 0; a < 4; a++) { f32x4 z = {0.f,0.f,0.f,0.f}; acc[a] = z; }

  #pragma unroll 2
  for (int kc = 0; kc < 32; kc++) {
    const int k0 = kbase + kc * 32 + q * 8;
    const float* src = &w6[(size_t)(n0 + ln) * K1 + k0];
    f32x4 v0 = *(const f32x4*)src;
    f32x4 v1 = *(const f32x4*)(src + 4);
    bf16x8 bfr;
    #pragma unroll
    for (int j = 0; j < 4; j++) { bfr[j] = (__bf16)v0[j]; bfr[4 + j] = (__bf16)v1[j]; }
    #pragma unroll
    for (int mi = 0; mi < 4; mi++) {
      bf16x8 af = *(const bf16x8*)&pooled[(size_t)(mi * 16 + ln) * K1 + k0];
      acc[mi] = mfma16(af, bfr, acc[mi]);
    }
  }
  #pragma unroll
  for (int mi = 0; mi < 4; mi++)
    #pragma unroll
    for (int r = 0; r < 4; r++)
      S1[(size_t)ks * (B_ * REP) + (size_t)(mi * 16 + q * 4 + r) * REP + n0 + ln] = acc[mi][r];
}

// ============================================================
// reduce1: h6b[m][n] = bf16(relu(sum_ks S1[ks][m][n] + b6[n]))
// ============================================================
__global__ __launch_bounds__(256)
void reduce1_kernel(const float* __restrict__ S1, const float* __restrict__ b6,
                    __bf16* __restrict__ h6b) {
  const int idx = blockIdx.x * 256 + threadIdx.x;
  float s = 0.f;
  #pragma unroll 8
  for (int ks = 0; ks < 64; ks++) s += S1[(size_t)ks * (B_ * REP) + idx];
  h6b[idx] = (__bf16)fmaxf(s + b6[idx & (REP - 1)], 0.f);
}

// ============================================================
// gemm2: S2[ks][m][n] partials of h6b @ w7^T. grid (16 nb, 32 ks), block 256.
// ============================================================
__global__ __launch_bounds__(256)
void gemm2_kernel(const __bf16* __restrict__ h6b, const float* __restrict__ w7,
                  float* __restrict__ S2) {
  const int nb = blockIdx.x, ks = blockIdx.y;
  const int t = threadIdx.x;
  const int wv = t >> 6;
  const int lane = t & 63;
  const int q = lane >> 4, ln = lane & 15;
  const int n0 = nb * 64 + wv * 16;
  const int k0 = ks * 32 + q * 8;

  const float* src = &w7[(size_t)(n0 + ln) * REP + k0];
  f32x4 v0 = *(const f32x4*)src;
  f32x4 v1 = *(const f32x4*)(src + 4);
  bf16x8 bfr;
  #pragma unroll
  for (int j = 0; j < 4; j++) { bfr[j] = (__bf16)v0[j]; bfr[4 + j] = (__bf16)v1[j]; }

  f32x4 acc[4];
  #pragma unroll
  for (int mi = 0; mi < 4; mi++) {
    f32x4 z = {0.f,0.f,0.f,0.f};
    bf16x8 af = *(const bf16x8*)&h6b[(size_t)(mi * 16 + ln) * REP + k0];
    acc[mi] = mfma16(af, bfr, z);
  }
  #pragma unroll
  for (int mi = 0; mi < 4; mi++)
    #pragma unroll
    for (int r = 0; r < 4; r++)
      S2[(size_t)ks * (B_ * REP) + (size_t)(mi * 16 + q * 4 + r) * REP + n0 + ln] = acc[mi][r];
}

// ============================================================
// reduce2: out[m][n] = relu(sum_ks S2 + b7[n])
// ============================================================
__global__ __launch_bounds__(256)
void reduce2_kernel(const float* __restrict__ S2, const float* __restrict__ b7,
                    float* __restrict__ out) {
  const int idx = blockIdx.x * 256 + threadIdx.x;
  float s = 0.f;
  #pragma unroll 8
  for (int ks = 0; ks < 32; ks++) s += S2[(size_t)ks * (B_ * REP) + idx];
  out[idx] = fmaxf(s + b7[idx & (REP - 1)], 0.f);
}

extern "C" void kernel_launch(void* const* d_in, const int* in_sizes, int n_in,
                              void* d_out, int out_size, void* d_ws, size_t ws_size,
                              hipStream_t stream) {
  const float* x   = (const float*)d_in[0];
  const float* cw  = (const float*)d_in[1];
  const float* cb  = (const float*)d_in[2];
  const float* w6  = (const float*)d_in[3];
  const float* b6  = (const float*)d_in[4];
  const float* w7  = (const float*)d_in[5];
  const float* b7  = (const float*)d_in[6];
  float* out = (float*)d_out;

  char* ws = (char*)d_ws;
  __bf16* xT     = (__bf16*)(ws + OFF_XT);   // later S1
  float*  S1     = (float*)(ws + OFF_XT);
  float*  S      = (float*)(ws + OFF_S);
  __bf16* pooled = (__bf16*)(ws + OFF_R2);   // later S2
  float*  S2     = (float*)(ws + OFF_R2);
  __bf16* W2     = (__bf16*)(ws + OFF_W2);
  float*  am     = (float*)(ws + OFF_AM);
  __bf16* h6b    = (__bf16*)(ws + OFF_H6B);

  prep_w2       <<<256,          256, 0, stream>>>(cw, W2);
  txp_kernel    <<<dim3(64, 64), 256, 0, stream>>>(x, xT);
  sgemm_kernel  <<<dim3(7, 64),  384, 0, stream>>>(xT, W2, S);
  combine_kernel<<<256,          256, 0, stream>>>(S, am);
  pooled_kernel <<<dim3(16, 64), 256, 0, stream>>>(x, am, cb, pooled);
  gemm1_kernel  <<<dim3(16, 64), 256, 0, stream>>>(pooled, w6, S1);
  reduce1_kernel<<<256,          256, 0, stream>>>(S1, b6, h6b);
  gemm2_kernel  <<<dim3(16, 32), 256, 0, stream>>>(h6b, w7, S2);
  reduce2_kernel<<<256,          256, 0, stream>>>(S2, b7, out);
}

// Round 4
// 579.829 us; speedup vs baseline: 1.2462x; 1.1299x over previous
//
#include <hip/hip_runtime.h>
#include <hip/hip_bf16.h>

#define B_   64
#define CIN  2048
#define COUT 32
#define P    196      // 14*14
#define PPAD 224      // padded pixel count
#define REP  1024
#define K1   (CIN*COUT)  // 65536

typedef float  f32x4  __attribute__((ext_vector_type(4)));
typedef __bf16 bf16x8 __attribute__((ext_vector_type(8)));
typedef __bf16 bf16x4 __attribute__((ext_vector_type(4)));

// ---- workspace layout (bytes) ----
#define OFF_W2     0                 // bf16 [9*32][2048]    (1.18MB)
#define OFF_AM     1310720           // f32  [64][32][224]   (1.84MB)  memset 0
#define OFF_POOLED 3145728           // bf16 [64][65536]     (8.39MB)
#define OFF_S1     11534336          // f32  [64][64][1024]  (16.8MB)
#define OFF_H6B    28311552          // bf16 [64][1024]      (131KB)
#define OFF_S2     28442624          // f32  [32][64][1024]  (8.39MB)

static __device__ __forceinline__ f32x4 mfma16(bf16x8 a, bf16x8 b, f32x4 c) {
  return __builtin_amdgcn_mfma_f32_16x16x32_bf16(a, b, c, 0, 0, 0);
}

// ============================================================
// prep_w2: cw[o][cin][d] f32 -> W2[d*32+o][cin] bf16
// ============================================================
__global__ __launch_bounds__(256)
void prep_w2(const float* __restrict__ cw, __bf16* __restrict__ W2) {
  const int blk = blockIdx.x;            // o*8 + cc
  const int o = blk >> 3, cc = blk & 7;
  const int cin = cc * 256 + threadIdx.x;
  const float* src = cw + ((size_t)o * CIN + cin) * 9;
  #pragma unroll
  for (int d = 0; d < 9; d++)
    W2[((size_t)d * COUT + o) * CIN + cin] = (__bf16)src[d];
}

// ============================================================
// conv: am[b][o][p] += sum over this block's 256-cin slice of
//   sum_{dy,dx} W[o][i][dy,dx] * xext[b][i][h+dy][w+dx]
// Fused implicit GEMM: LDS holds zero-padded 16x16 ext image tile
// (bf16, [256 rows][64 ic + 8 pad]); 9 taps accumulate into the same
// MFMA acc via shifted LDS row reads. A (tap weights) streamed from
// L2-resident W2 (vector-mem pipe, overlaps LDS pipe).
// grid (8 k-slices, 64 b), block 448 (7 waves); wave = 2 p-tiles x 2 o-tiles.
// ============================================================
#define ICW 72   // LDS row stride in elements (64 ic + 8 pad -> conflict-free)
__global__ __launch_bounds__(448)
void conv_kernel(const float* __restrict__ x, const __bf16* __restrict__ W2,
                 float* __restrict__ am) {
  __shared__ __bf16 XT[256 * ICW];       // 36.9 KB

  const int ksl = blockIdx.x;            // 256-cin slice
  const int b   = blockIdx.y;
  const int t   = threadIdx.x;
  const int wv  = t >> 6;                // 0..6
  const int lane = t & 63;
  const int q = lane >> 4, ln = lane & 15;
  const float* xb = x + (size_t)b * CIN * P;
  const int kbase = ksl * 256;

  // per-wave pixel geometry (2 n-tiles of 16 pixels)
  int  rb[2];  bool valid[2];  int pix[2];
  #pragma unroll
  for (int nt = 0; nt < 2; nt++) {
    const int pt = wv * 32 + nt * 16 + ln;
    pix[nt] = pt;  valid[nt] = (pt < P);
    const int pr = valid[nt] ? pt : 0;
    const int h = pr / 14, w = pr - (pr / 14) * 14;
    rb[nt] = (h + 1) * 16 + (w + 1);     // center-tap ext row
  }
  // tap row offsets: (dy-1)*16 + (dx-1)
  f32x4 acc[2][2];
  #pragma unroll
  for (int m = 0; m < 2; m++)
    #pragma unroll
    for (int n = 0; n < 2; n++) { f32x4 z = {0.f,0.f,0.f,0.f}; acc[m][n] = z; }

  // zero border rows once (they are never overwritten by staging)
  for (int row = t; row < 256; row += 448) {
    const int hh = row >> 4, ww = row & 15;
    if (hh == 0 || hh == 15 || ww == 0 || ww == 15) {
      #pragma unroll
      for (int g = 0; g < 8; g++) {
        bf16x8 z = {};
        *(bf16x8*)&XT[row * ICW + g * 8] = z;
      }
    }
  }

  for (int sub = 0; sub < 4; sub++) {    // 4 sub-chunks of 64 cin
    const int i0 = kbase + sub * 64;
    __syncthreads();                     // prev compute done (covers border init too)
    // stage interior: unit = g*196 + p  (consecutive t -> consecutive p: coalesced)
    for (int u = t; u < 1568; u += 448) {
      const int g = u / 196, p = u - g * 196;
      const int h = p / 14, w = p - (p / 14) * 14;
      bf16x8 v;
      #pragma unroll
      for (int j = 0; j < 8; j++)
        v[j] = (__bf16)xb[(size_t)(i0 + g * 8 + j) * P + p];
      *(bf16x8*)&XT[((h + 1) * 16 + (w + 1)) * ICW + g * 8] = v;
    }
    __syncthreads();

    #pragma unroll
    for (int ks2 = 0; ks2 < 2; ks2++) {  // 2 k-steps of 32
      const int kg  = i0 + ks2 * 32 + q * 8;       // global k for A
      const int off = (ks2 * 4 + q) * 8;           // LDS element offset for B
      #pragma unroll
      for (int d = 0; d < 9; d++) {
        const int dy = d / 3, dx = d - (d / 3) * 3;
        const int delta = (dy - 1) * 16 + (dx - 1);
        bf16x8 a0 = *(const bf16x8*)&W2[(size_t)(d * COUT + ln) * CIN + kg];
        bf16x8 a1 = *(const bf16x8*)&W2[(size_t)(d * COUT + 16 + ln) * CIN + kg];
        #pragma unroll
        for (int nt = 0; nt < 2; nt++) {
          bf16x8 bf = *(const bf16x8*)&XT[(rb[nt] + delta) * ICW + off];
          acc[0][nt] = mfma16(a0, bf, acc[0][nt]);
          acc[1][nt] = mfma16(a1, bf, acc[1][nt]);
        }
      }
    }
  }

  // epilogue: atomic accumulate into am (8 k-slice blocks contend)
  #pragma unroll
  for (int mt = 0; mt < 2; mt++)
    #pragma unroll
    for (int nt = 0; nt < 2; nt++)
      if (valid[nt]) {
        #pragma unroll
        for (int r = 0; r < 4; r++) {
          const int o = mt * 16 + q * 4 + r;
          atomicAdd(&am[((size_t)b * COUT + o) * PPAD + pix[nt]], acc[mt][nt][r]);
        }
      }
}

// ============================================================
// pooled[b][i*32+o] = bf16( (1/196) sum_p (am[b,o,p]+cb[o]) * x[b,i,p] )
// grid (16, 64), block 256; wave: 32 i x 32 o. am pad region is zero.
// ============================================================
__global__ __launch_bounds__(256)
void pooled_kernel(const float* __restrict__ x, const float* __restrict__ amp,
                   const float* __restrict__ cb, __bf16* __restrict__ pooled) {
  const int b  = blockIdx.y;
  const int ig = blockIdx.x;
  const int t  = threadIdx.x;
  const int wv = t >> 6;
  const int lane = t & 63;
  const int q = lane >> 4, ln = lane & 15;
  const int ibase = ig * 128 + wv * 32;

  f32x4 acc[2][2];
  #pragma unroll
  for (int a = 0; a < 2; a++)
    #pragma unroll
    for (int c = 0; c < 2; c++) { f32x4 z = {0.f,0.f,0.f,0.f}; acc[a][c] = z; }

  const float* amb = amp + (size_t)b * COUT * PPAD;
  const float* xb  = x + (size_t)b * CIN * P;
  const float cbv[2] = { cb[ln], cb[16 + ln] };

  for (int kc = 0; kc < 7; kc++) {
    const int k0 = kc * 32 + q * 8;
    bf16x8 af[2];
    #pragma unroll
    for (int o2 = 0; o2 < 2; o2++) {
      const float* src = &amb[(size_t)(o2 * 16 + ln) * PPAD + k0];
      f32x4 v0 = *(const f32x4*)src;
      f32x4 v1 = *(const f32x4*)(src + 4);
      bf16x8 a;
      #pragma unroll
      for (int j = 0; j < 4; j++) { a[j] = (__bf16)(v0[j] + cbv[o2]); a[4 + j] = (__bf16)(v1[j] + cbv[o2]); }
      af[o2] = a;
    }
    #pragma unroll
    for (int it = 0; it < 2; it++) {
      const int i = ibase + it * 16 + ln;
      bf16x8 bfr;
      if (kc < 6) {
        const float* src = &xb[(size_t)i * P + k0];
        f32x4 v0 = *(const f32x4*)src;
        f32x4 v1 = *(const f32x4*)(src + 4);
        #pragma unroll
        for (int j = 0; j < 4; j++) { bfr[j] = (__bf16)v0[j]; bfr[4 + j] = (__bf16)v1[j]; }
      } else {
        #pragma unroll
        for (int j = 0; j < 8; j++) {
          const int p = k0 + j;
          bfr[j] = (p < P) ? (__bf16)xb[(size_t)i * P + p] : (__bf16)0.f;
        }
      }
      acc[0][it] = mfma16(af[0], bfr, acc[0][it]);
      acc[1][it] = mfma16(af[1], bfr, acc[1][it]);
    }
  }

  const float sc = 1.0f / 196.0f;
  #pragma unroll
  for (int o2 = 0; o2 < 2; o2++)
    #pragma unroll
    for (int it = 0; it < 2; it++) {
      const int i = ibase + it * 16 + ln;
      bf16x4 vv;
      #pragma unroll
      for (int r = 0; r < 4; r++) vv[r] = (__bf16)(acc[o2][it][r] * sc);
      *(bf16x4*)&pooled[(size_t)b * K1 + (size_t)i * COUT + o2 * 16 + q * 4] = vv;
    }
}

// ============================================================
// gemm1: S1[ks][m][n] = pooled[m][ks-range] @ w6[n][ks-range]^T
// grid (16 nb, 64 ks), block 256. No atomics.
// ============================================================
__global__ __launch_bounds__(256)
void gemm1_kernel(const __bf16* __restrict__ pooled, const float* __restrict__ w6,
                  float* __restrict__ S1) {
  const int nb = blockIdx.x, ks = blockIdx.y;
  const int t = threadIdx.x;
  const int wv = t >> 6;
  const int lane = t & 63;
  const int q = lane >> 4, ln = lane & 15;
  const int n0 = nb * 64 + wv * 16;
  const int kbase = ks * 1024;

  f32x4 acc[4];
  #pragma unroll
  for (int a = 0; a < 4; a++) { f32x4 z = {0.f,0.f,0.f,0.f}; acc[a] = z; }

  #pragma unroll 2
  for (int kc = 0; kc < 32; kc++) {
    const int k0 = kbase + kc * 32 + q * 8;
    const float* src = &w6[(size_t)(n0 + ln) * K1 + k0];
    f32x4 v0 = *(const f32x4*)src;
    f32x4 v1 = *(const f32x4*)(src + 4);
    bf16x8 bfr;
    #pragma unroll
    for (int j = 0; j < 4; j++) { bfr[j] = (__bf16)v0[j]; bfr[4 + j] = (__bf16)v1[j]; }
    #pragma unroll
    for (int mi = 0; mi < 4; mi++) {
      bf16x8 af = *(const bf16x8*)&pooled[(size_t)(mi * 16 + ln) * K1 + k0];
      acc[mi] = mfma16(af, bfr, acc[mi]);
    }
  }
  #pragma unroll
  for (int mi = 0; mi < 4; mi++)
    #pragma unroll
    for (int r = 0; r < 4; r++)
      S1[(size_t)ks * (B_ * REP) + (size_t)(mi * 16 + q * 4 + r) * REP + n0 + ln] = acc[mi][r];
}

// ============================================================
// reduce1: h6b[m][n] = bf16(relu(sum_ks S1[ks][m][n] + b6[n]))
// ============================================================
__global__ __launch_bounds__(256)
void reduce1_kernel(const float* __restrict__ S1, const float* __restrict__ b6,
                    __bf16* __restrict__ h6b) {
  const int idx = blockIdx.x * 256 + threadIdx.x;
  float s = 0.f;
  #pragma unroll 8
  for (int ks = 0; ks < 64; ks++) s += S1[(size_t)ks * (B_ * REP) + idx];
  h6b[idx] = (__bf16)fmaxf(s + b6[idx & (REP - 1)], 0.f);
}

// ============================================================
// gemm2: S2[ks][m][n] partials of h6b @ w7^T. grid (16 nb, 32 ks), block 256.
// ============================================================
__global__ __launch_bounds__(256)
void gemm2_kernel(const __bf16* __restrict__ h6b, const float* __restrict__ w7,
                  float* __restrict__ S2) {
  const int nb = blockIdx.x, ks = blockIdx.y;
  const int t = threadIdx.x;
  const int wv = t >> 6;
  const int lane = t & 63;
  const int q = lane >> 4, ln = lane & 15;
  const int n0 = nb * 64 + wv * 16;
  const int k0 = ks * 32 + q * 8;

  const float* src = &w7[(size_t)(n0 + ln) * REP + k0];
  f32x4 v0 = *(const f32x4*)src;
  f32x4 v1 = *(const f32x4*)(src + 4);
  bf16x8 bfr;
  #pragma unroll
  for (int j = 0; j < 4; j++) { bfr[j] = (__bf16)v0[j]; bfr[4 + j] = (__bf16)v1[j]; }

  f32x4 acc[4];
  #pragma unroll
  for (int mi = 0; mi < 4; mi++) {
    f32x4 z = {0.f,0.f,0.f,0.f};
    bf16x8 af = *(const bf16x8*)&h6b[(size_t)(mi * 16 + ln) * REP + k0];
    acc[mi] = mfma16(af, bfr, z);
  }
  #pragma unroll
  for (int mi = 0; mi < 4; mi++)
    #pragma unroll
    for (int r = 0; r < 4; r++)
      S2[(size_t)ks * (B_ * REP) + (size_t)(mi * 16 + q * 4 + r) * REP + n0 + ln] = acc[mi][r];
}

// ============================================================
// reduce2: out[m][n] = relu(sum_ks S2 + b7[n])
// ============================================================
__global__ __launch_bounds__(256)
void reduce2_kernel(const float* __restrict__ S2, const float* __restrict__ b7,
                    float* __restrict__ out) {
  const int idx = blockIdx.x * 256 + threadIdx.x;
  float s = 0.f;
  #pragma unroll 8
  for (int ks = 0; ks < 32; ks++) s += S2[(size_t)ks * (B_ * REP) + idx];
  out[idx] = fmaxf(s + b7[idx & (REP - 1)], 0.f);
}

extern "C" void kernel_launch(void* const* d_in, const int* in_sizes, int n_in,
                              void* d_out, int out_size, void* d_ws, size_t ws_size,
                              hipStream_t stream) {
  const float* x   = (const float*)d_in[0];
  const float* cw  = (const float*)d_in[1];
  const float* cb  = (const float*)d_in[2];
  const float* w6  = (const float*)d_in[3];
  const float* b6  = (const float*)d_in[4];
  const float* w7  = (const float*)d_in[5];
  const float* b7  = (const float*)d_in[6];
  float* out = (float*)d_out;

  char* ws = (char*)d_ws;
  __bf16* W2     = (__bf16*)(ws + OFF_W2);
  float*  am     = (float*)(ws + OFF_AM);
  __bf16* pooled = (__bf16*)(ws + OFF_POOLED);
  float*  S1     = (float*)(ws + OFF_S1);
  __bf16* h6b    = (__bf16*)(ws + OFF_H6B);
  float*  S2     = (float*)(ws + OFF_S2);

  hipMemsetAsync(am, 0, (size_t)B_ * COUT * PPAD * 4, stream);
  prep_w2       <<<256,          256, 0, stream>>>(cw, W2);
  conv_kernel   <<<dim3(8, 64),  448, 0, stream>>>(x, W2, am);
  pooled_kernel <<<dim3(16, 64), 256, 0, stream>>>(x, am, cb, pooled);
  gemm1_kernel  <<<dim3(16, 64), 256, 0, stream>>>(pooled, w6, S1);
  reduce1_kernel<<<256,          256, 0, stream>>>(S1, b6, h6b);
  gemm2_kernel  <<<dim3(16, 32), 256, 0, stream>>>(h6b, w7, S2);
  reduce2_kernel<<<256,          256, 0, stream>>>(S2, b7, out);
}